// Round 2
// baseline (1079.076 us; speedup 1.0000x reference)
//
#include <hip/hip_runtime.h>
#include <hip/hip_bf16.h>
#include <math.h>

// Problem constants (AydinConfig: H=1024, I=2048, E=8, K=2; B=4, S=2048)
#define NEXP 8
#define HD 1024
#define ID 2048
#define NTOK 8192          // B*S
#define NROWS 16384        // NTOK * top_k

typedef __bf16 bf16_t;
typedef __bf16 bf16x8 __attribute__((ext_vector_type(8)));
typedef float f32x4 __attribute__((ext_vector_type(4)));

// GEMM tiling: 128x64 tile, BK=32, 256 threads (4 waves), each wave 64x32
#define BM 128
#define BN 64
#define BK 32
#define PK 40              // padded LDS k-stride (80 B: 16B-aligned, conflict-friendly)
#define MT_MAX 64          // 8192 / BM worst-case M-tiles per expert

// ---------------------------------------------------------------- router ----
__global__ __launch_bounds__(256)
void router_kernel(const float* __restrict__ x, const float* __restrict__ rw,
                   bf16_t* __restrict__ xb, int* __restrict__ topk_idx,
                   float* __restrict__ topk_w, int* __restrict__ counts)
{
    const int t = blockIdx.x;
    const int tid = threadIdx.x;
    const float4 xv = ((const float4*)(x + (size_t)t * HD))[tid];
    float acc[NEXP];
#pragma unroll
    for (int e = 0; e < NEXP; ++e) {
        const float4 w4 = ((const float4*)(rw + e * HD))[tid];
        acc[e] = xv.x * w4.x + xv.y * w4.y + xv.z * w4.z + xv.w * w4.w;
    }
    // fused fp32 -> bf16 cast of x
    bf16_t tmp[4] = {(bf16_t)xv.x, (bf16_t)xv.y, (bf16_t)xv.z, (bf16_t)xv.w};
    *(uint2*)(xb + (size_t)t * HD + tid * 4) = *(const uint2*)tmp;

    __shared__ float red[4][NEXP];
    const int lane = tid & 63, wv = tid >> 6;
#pragma unroll
    for (int e = 0; e < NEXP; ++e) {
        float v = acc[e];
#pragma unroll
        for (int off = 32; off >= 1; off >>= 1) v += __shfl_down(v, off, 64);
        if (lane == 0) red[wv][e] = v;
    }
    __syncthreads();
    if (tid == 0) {
        float lg[NEXP], mx = -1e30f;
#pragma unroll
        for (int e = 0; e < NEXP; ++e) {
            lg[e] = red[0][e] + red[1][e] + red[2][e] + red[3][e];
            mx = fmaxf(mx, lg[e]);
        }
        float p[NEXP], s = 0.f;
#pragma unroll
        for (int e = 0; e < NEXP; ++e) { p[e] = __expf(lg[e] - mx); s += p[e]; }
        const float inv = 1.f / s;
#pragma unroll
        for (int e = 0; e < NEXP; ++e) p[e] *= inv;
        // top-2, ties -> lower index (matches lax.top_k)
        int i0 = 0; float p0 = p[0];
#pragma unroll
        for (int e = 1; e < NEXP; ++e) if (p[e] > p0) { p0 = p[e]; i0 = e; }
        int i1 = -1; float p1 = -1.f;
#pragma unroll
        for (int e = 0; e < NEXP; ++e) if (e != i0 && p[e] > p1) { p1 = p[e]; i1 = e; }
        const float d = 1.f / (p0 + p1 + 1e-6f);
        topk_idx[t * 2 + 0] = i0; topk_idx[t * 2 + 1] = i1;
        topk_w[t * 2 + 0] = p0 * d; topk_w[t * 2 + 1] = p1 * d;
        atomicAdd(&counts[i0], 1);
        atomicAdd(&counts[i1], 1);
    }
}

// ------------------------------------------------------------------ scan ----
__global__ void scan_kernel(const int* __restrict__ counts,
                            int* __restrict__ offsets, int* __restrict__ cursor)
{
    if (threadIdx.x == 0 && blockIdx.x == 0) {
        int s = 0;
#pragma unroll
        for (int e = 0; e < NEXP; ++e) { offsets[e] = s; cursor[e] = s; s += counts[e]; }
    }
}

// --------------------------------------------------------------- scatter ----
__global__ __launch_bounds__(256)
void scatter_kernel(const int* __restrict__ topk_idx, const float* __restrict__ topk_w,
                    int* __restrict__ cursor, int* __restrict__ token_list,
                    float* __restrict__ row_w)
{
    const int t = blockIdx.x * 256 + threadIdx.x;
    if (t >= NTOK) return;
#pragma unroll
    for (int k = 0; k < 2; ++k) {
        const int e = topk_idx[t * 2 + k];
        const int pos = atomicAdd(&cursor[e], 1);
        token_list[pos] = t;
        row_w[pos] = topk_w[t * 2 + k];
    }
}

// ------------------------------------------------- grouped GEMM1 + SwiGLU ----
// h[row, n] = silu(x_row . w13[e][:, n]) * (x_row . w13[e][:, n+ID])
__global__ __launch_bounds__(256)
void gemm1_kernel(const bf16_t* __restrict__ xb, const float* __restrict__ w13,
                  const int* __restrict__ offsets, const int* __restrict__ counts,
                  const int* __restrict__ token_list, bf16_t* __restrict__ hbuf)
{
    const int e = blockIdx.y >> 6;          // / MT_MAX
    const int mt = blockIdx.y & (MT_MAX - 1);
    const int rows = counts[e];
    const int r0 = mt * BM;
    if (r0 >= rows) return;
    const int row_base = offsets[e];
    const int n0 = blockIdx.x * BN;

    __shared__ int tok_s[BM];
    __shared__ alignas(16) bf16_t As[BM][PK];
    __shared__ alignas(16) bf16_t Bg[BN][PK];
    __shared__ alignas(16) bf16_t Bu[BN][PK];

    const int tid = threadIdx.x;
    if (tid < BM) {
        int gr = row_base + r0 + tid;
        if (gr > NROWS - 1) gr = NROWS - 1;   // clamp: padded rows guarded at write
        tok_s[tid] = token_list[gr];
    }
    __syncthreads();

    const int lane = tid & 63, wv = tid >> 6;
    const int wr = wv >> 1, wc = wv & 1;
    const int ln15 = lane & 15, q = lane >> 4;

    f32x4 accG[4][2], accU[4][2];
#pragma unroll
    for (int i = 0; i < 4; ++i)
#pragma unroll
        for (int j = 0; j < 2; ++j)
#pragma unroll
            for (int c = 0; c < 4; ++c) { accG[i][j][c] = 0.f; accU[i][j][c] = 0.f; }

    const float* w13e = w13 + (size_t)e * HD * (2 * ID);
    // A staging: 2 threads per row, each covers 16 bf16 elements = 32 B (2x uint4)
    const int ar = tid >> 1, ac = (tid & 1) * 16;
    const int bk = tid >> 4, bn = (tid & 15) * 4;  // B staging: float4 along n

    for (int k0 = 0; k0 < HD; k0 += BK) {
        const uint4* asrc = (const uint4*)(xb + (size_t)tok_s[ar] * HD + k0 + ac);
        *(uint4*)&As[ar][ac]     = asrc[0];
        *(uint4*)&As[ar][ac + 8] = asrc[1];
        // stage B gate+up: fp32 load, cvt, transposed b16 writes ([n][k] layout)
#pragma unroll
        for (int s = 0; s < 2; ++s) {
            const int kk = bk + 16 * s;
            const float* src = w13e + (size_t)(k0 + kk) * (2 * ID) + n0 + bn;
            const float4 g4 = *(const float4*)src;
            const float4 u4 = *(const float4*)(src + ID);
            Bg[bn + 0][kk] = (bf16_t)g4.x; Bg[bn + 1][kk] = (bf16_t)g4.y;
            Bg[bn + 2][kk] = (bf16_t)g4.z; Bg[bn + 3][kk] = (bf16_t)g4.w;
            Bu[bn + 0][kk] = (bf16_t)u4.x; Bu[bn + 1][kk] = (bf16_t)u4.y;
            Bu[bn + 2][kk] = (bf16_t)u4.z; Bu[bn + 3][kk] = (bf16_t)u4.w;
        }
        __syncthreads();

        bf16x8 af[4];
#pragma unroll
        for (int i = 0; i < 4; ++i)
            af[i] = *(const bf16x8*)&As[wr * 64 + i * 16 + ln15][q * 8];
        bf16x8 bg[2], bu[2];
#pragma unroll
        for (int j = 0; j < 2; ++j) {
            bg[j] = *(const bf16x8*)&Bg[wc * 32 + j * 16 + ln15][q * 8];
            bu[j] = *(const bf16x8*)&Bu[wc * 32 + j * 16 + ln15][q * 8];
        }
#pragma unroll
        for (int i = 0; i < 4; ++i)
#pragma unroll
            for (int j = 0; j < 2; ++j) {
                accG[i][j] = __builtin_amdgcn_mfma_f32_16x16x32_bf16(af[i], bg[j], accG[i][j], 0, 0, 0);
                accU[i][j] = __builtin_amdgcn_mfma_f32_16x16x32_bf16(af[i], bu[j], accU[i][j], 0, 0, 0);
            }
        __syncthreads();
    }

    // epilogue: SwiGLU in fp32, store bf16 h. C/D: col=lane&15, row=q*4+reg
#pragma unroll
    for (int i = 0; i < 4; ++i) {
#pragma unroll
        for (int reg = 0; reg < 4; ++reg) {
            const int rr = wr * 64 + i * 16 + q * 4 + reg;
            if (r0 + rr < rows) {
                bf16_t* dst = hbuf + (size_t)(row_base + r0 + rr) * ID + n0 + wc * 32 + ln15;
#pragma unroll
                for (int j = 0; j < 2; ++j) {
                    const float g = accG[i][j][reg], u = accU[i][j][reg];
                    dst[j * 16] = (bf16_t)((g / (1.f + __expf(-g))) * u);
                }
            }
        }
    }
}

// --------------------------------------------------------- grouped GEMM2 ----
// out[token, n] += weight_row * (h_row . w2[e][:, n])
__global__ __launch_bounds__(256)
void gemm2_kernel(const bf16_t* __restrict__ hbuf, const float* __restrict__ w2,
                  const int* __restrict__ offsets, const int* __restrict__ counts,
                  const int* __restrict__ token_list, const float* __restrict__ row_w,
                  float* __restrict__ out)
{
    const int e = blockIdx.y >> 6;
    const int mt = blockIdx.y & (MT_MAX - 1);
    const int rows = counts[e];
    const int r0 = mt * BM;
    if (r0 >= rows) return;
    const int row_base = offsets[e];
    const int n0 = blockIdx.x * BN;

    __shared__ int tok_s[BM];
    __shared__ float rww_s[BM];
    __shared__ alignas(16) bf16_t As[BM][PK];
    __shared__ alignas(16) bf16_t Bs[BN][PK];

    const int tid = threadIdx.x;
    if (tid < BM) {
        int gr = row_base + r0 + tid;
        if (gr > NROWS - 1) gr = NROWS - 1;
        tok_s[tid] = token_list[gr];
        rww_s[tid] = row_w[gr];
    }
    __syncthreads();

    const int lane = tid & 63, wv = tid >> 6;
    const int wr = wv >> 1, wc = wv & 1;
    const int ln15 = lane & 15, q = lane >> 4;

    f32x4 acc[4][2];
#pragma unroll
    for (int i = 0; i < 4; ++i)
#pragma unroll
        for (int j = 0; j < 2; ++j)
#pragma unroll
            for (int c = 0; c < 4; ++c) acc[i][j][c] = 0.f;

    const float* w2e = w2 + (size_t)e * ID * HD;
    const int ar = tid >> 1, ac = (tid & 1) * 16;
    const int bk = tid >> 4, bn = (tid & 15) * 4;
    int grow = row_base + r0 + ar;
    if (grow > NROWS - 1) grow = NROWS - 1;
    const bf16_t* arow = hbuf + (size_t)grow * ID;

    for (int k0 = 0; k0 < ID; k0 += BK) {
        const uint4* asrc = (const uint4*)(arow + k0 + ac);
        *(uint4*)&As[ar][ac]     = asrc[0];
        *(uint4*)&As[ar][ac + 8] = asrc[1];
#pragma unroll
        for (int s = 0; s < 2; ++s) {
            const int kk = bk + 16 * s;
            const float4 b4 = *(const float4*)(w2e + (size_t)(k0 + kk) * HD + n0 + bn);
            Bs[bn + 0][kk] = (bf16_t)b4.x; Bs[bn + 1][kk] = (bf16_t)b4.y;
            Bs[bn + 2][kk] = (bf16_t)b4.z; Bs[bn + 3][kk] = (bf16_t)b4.w;
        }
        __syncthreads();

        bf16x8 af[4];
#pragma unroll
        for (int i = 0; i < 4; ++i)
            af[i] = *(const bf16x8*)&As[wr * 64 + i * 16 + ln15][q * 8];
        bf16x8 bf2[2];
#pragma unroll
        for (int j = 0; j < 2; ++j)
            bf2[j] = *(const bf16x8*)&Bs[wc * 32 + j * 16 + ln15][q * 8];
#pragma unroll
        for (int i = 0; i < 4; ++i)
#pragma unroll
            for (int j = 0; j < 2; ++j)
                acc[i][j] = __builtin_amdgcn_mfma_f32_16x16x32_bf16(af[i], bf2[j], acc[i][j], 0, 0, 0);
        __syncthreads();
    }

    // epilogue: scale by routing weight, atomicAdd into out (2 writers/elem)
#pragma unroll
    for (int i = 0; i < 4; ++i) {
#pragma unroll
        for (int reg = 0; reg < 4; ++reg) {
            const int rr = wr * 64 + i * 16 + q * 4 + reg;
            if (r0 + rr < rows) {
                const float w = rww_s[rr];
                float* dst = out + (size_t)tok_s[rr] * HD + n0 + wc * 32 + ln15;
#pragma unroll
                for (int j = 0; j < 2; ++j)
                    atomicAdd(&dst[j * 16], acc[i][j][reg] * w);
            }
        }
    }
}

// ---------------------------------------------------------------- launch ----
extern "C" void kernel_launch(void* const* d_in, const int* in_sizes, int n_in,
                              void* d_out, int out_size, void* d_ws, size_t ws_size,
                              hipStream_t stream) {
    const float* x   = (const float*)d_in[0];   // (4,2048,1024)
    const float* rw  = (const float*)d_in[1];   // (8,1024)
    const float* w13 = (const float*)d_in[2];   // (8,1024,4096)
    const float* w2  = (const float*)d_in[3];   // (8,2048,1024)
    float* out = (float*)d_out;                 // (4,2048,1024) fp32

    char* ws = (char*)d_ws;
    // ws layout (~81 MB total)
    int*   counts     = (int*)(ws + 0);
    int*   cursor     = (int*)(ws + 64);
    int*   offsets    = (int*)(ws + 128);
    int*   topk_idx   = (int*)(ws + 256);
    float* topk_w     = (float*)(ws + 256 + 1 * 65536);
    int*   token_list = (int*)(ws + 256 + 2 * 65536);
    float* row_w      = (float*)(ws + 256 + 3 * 65536);
    bf16_t* xb        = (bf16_t*)(ws + (size_t)1024 * 1024);                        // 16 MB
    bf16_t* hbuf      = (bf16_t*)(ws + (size_t)1024 * 1024 + (size_t)NTOK * HD * 2); // 64 MB

    hipMemsetAsync(ws, 0, 256, stream);                              // counts/cursor
    hipMemsetAsync(d_out, 0, (size_t)out_size * sizeof(float), stream);

    router_kernel<<<NTOK, 256, 0, stream>>>(x, rw, xb, topk_idx, topk_w, counts);
    scan_kernel<<<1, 64, 0, stream>>>(counts, offsets, cursor);
    scatter_kernel<<<NTOK / 256, 256, 0, stream>>>(topk_idx, topk_w, cursor, token_list, row_w);

    dim3 g1(ID / BN, NEXP * MT_MAX);    // 32 x 512
    gemm1_kernel<<<g1, 256, 0, stream>>>(xb, w13, offsets, counts, token_list, hbuf);
    dim3 g2(HD / BN, NEXP * MT_MAX);    // 16 x 512
    gemm2_kernel<<<g2, 256, 0, stream>>>(hbuf, w2, offsets, counts, token_list, row_w, out);
}

// Round 3
// 916.731 us; speedup vs baseline: 1.1771x; 1.1771x over previous
//
#include <hip/hip_runtime.h>
#include <hip/hip_bf16.h>
#include <math.h>

// Problem constants (AydinConfig: H=1024, I=2048, E=8, K=2; B=4, S=2048)
#define NEXP 8
#define HD 1024
#define ID 2048
#define NTOK 8192          // B*S
#define NROWS 16384        // NTOK * top_k

typedef __bf16 bf16_t;
typedef __bf16 bf16x8 __attribute__((ext_vector_type(8)));
typedef float f32x4 __attribute__((ext_vector_type(4)));

// GEMM tiling: 128x64 tile, BK=32, 256 threads (4 waves), each wave 64x32
#define BM 128
#define BN 64
#define BK 32
#define PK 40              // padded LDS k-stride (80 B: 16B-aligned; frag reads/writes ~2-way = free)
#define MT_MAX 64          // 8192 / BM worst-case M-tiles per expert

// ---------------------------------------------------------------- router ----
__global__ __launch_bounds__(256)
void router_kernel(const float* __restrict__ x, const float* __restrict__ rw,
                   bf16_t* __restrict__ xb, int* __restrict__ topk_idx,
                   float* __restrict__ topk_w, int* __restrict__ counts)
{
    const int t = blockIdx.x;
    const int tid = threadIdx.x;
    const float4 xv = ((const float4*)(x + (size_t)t * HD))[tid];
    float acc[NEXP];
#pragma unroll
    for (int e = 0; e < NEXP; ++e) {
        const float4 w4 = ((const float4*)(rw + e * HD))[tid];
        acc[e] = xv.x * w4.x + xv.y * w4.y + xv.z * w4.z + xv.w * w4.w;
    }
    // fused fp32 -> bf16 cast of x
    bf16_t tmp[4] = {(bf16_t)xv.x, (bf16_t)xv.y, (bf16_t)xv.z, (bf16_t)xv.w};
    *(uint2*)(xb + (size_t)t * HD + tid * 4) = *(const uint2*)tmp;

    __shared__ float red[4][NEXP];
    const int lane = tid & 63, wv = tid >> 6;
#pragma unroll
    for (int e = 0; e < NEXP; ++e) {
        float v = acc[e];
#pragma unroll
        for (int off = 32; off >= 1; off >>= 1) v += __shfl_down(v, off, 64);
        if (lane == 0) red[wv][e] = v;
    }
    __syncthreads();
    if (tid == 0) {
        float lg[NEXP], mx = -1e30f;
#pragma unroll
        for (int e = 0; e < NEXP; ++e) {
            lg[e] = red[0][e] + red[1][e] + red[2][e] + red[3][e];
            mx = fmaxf(mx, lg[e]);
        }
        float p[NEXP], s = 0.f;
#pragma unroll
        for (int e = 0; e < NEXP; ++e) { p[e] = __expf(lg[e] - mx); s += p[e]; }
        const float inv = 1.f / s;
#pragma unroll
        for (int e = 0; e < NEXP; ++e) p[e] *= inv;
        // top-2, ties -> lower index (matches lax.top_k)
        int i0 = 0; float p0 = p[0];
#pragma unroll
        for (int e = 1; e < NEXP; ++e) if (p[e] > p0) { p0 = p[e]; i0 = e; }
        int i1 = -1; float p1 = -1.f;
#pragma unroll
        for (int e = 0; e < NEXP; ++e) if (e != i0 && p[e] > p1) { p1 = p[e]; i1 = e; }
        const float d = 1.f / (p0 + p1 + 1e-6f);
        topk_idx[t * 2 + 0] = i0; topk_idx[t * 2 + 1] = i1;
        topk_w[t * 2 + 0] = p0 * d; topk_w[t * 2 + 1] = p1 * d;
        atomicAdd(&counts[i0], 1);
        atomicAdd(&counts[i1], 1);
    }
}

// ------------------------------------------------------------------ scan ----
__global__ void scan_kernel(const int* __restrict__ counts,
                            int* __restrict__ offsets, int* __restrict__ cursor)
{
    if (threadIdx.x == 0 && blockIdx.x == 0) {
        int s = 0;
#pragma unroll
        for (int e = 0; e < NEXP; ++e) { offsets[e] = s; cursor[e] = s; s += counts[e]; }
    }
}

// --------------------------------------------------------------- scatter ----
__global__ __launch_bounds__(256)
void scatter_kernel(const int* __restrict__ topk_idx, const float* __restrict__ topk_w,
                    int* __restrict__ cursor, int* __restrict__ token_list,
                    float* __restrict__ row_w)
{
    const int t = blockIdx.x * 256 + threadIdx.x;
    if (t >= NTOK) return;
#pragma unroll
    for (int k = 0; k < 2; ++k) {
        const int e = topk_idx[t * 2 + k];
        const int pos = atomicAdd(&cursor[e], 1);
        token_list[pos] = t;
        row_w[pos] = topk_w[t * 2 + k];
    }
}

// -------------------------------------------------------- precast weights ----
// src: fp32 [K][N] per expert -> dst: bf16 [N][K] per expert (transpose + cast)
// 64x64 tiles via LDS; coalesced fp32 reads, coalesced 16B bf16 writes.
__global__ __launch_bounds__(256)
void precast_kernel(const float* __restrict__ src, bf16_t* __restrict__ dst,
                    int K, int N)
{
    const int e = blockIdx.z;
    src += (size_t)e * K * N;
    dst += (size_t)e * K * N;
    const int n0 = blockIdx.x * 64, k0 = blockIdx.y * 64;
    __shared__ float tile[64][65];   // +1 pad: transposed col reads conflict-free
    const int tid = threadIdx.x;
    const int tx = (tid & 15) * 4, ty = tid >> 4;
#pragma unroll
    for (int p = 0; p < 4; ++p) {
        const float4 v = *(const float4*)(src + (size_t)(k0 + ty + p * 16) * N + n0 + tx);
        tile[ty + p * 16][tx + 0] = v.x;
        tile[ty + p * 16][tx + 1] = v.y;
        tile[ty + p * 16][tx + 2] = v.z;
        tile[ty + p * 16][tx + 3] = v.w;
    }
    __syncthreads();
    const int n = tid >> 2, kc = (tid & 3) * 16;
    bf16_t outv[16];
#pragma unroll
    for (int j = 0; j < 16; ++j) outv[j] = (bf16_t)tile[kc + j][n];
    bf16_t* d = dst + (size_t)(n0 + n) * K + k0 + kc;
    *(uint4*)d = *(uint4*)outv;
    *(uint4*)(d + 8) = *((uint4*)outv + 1);
}

// ------------------------------------------------- grouped GEMM1 + SwiGLU ----
// h[row, n] = silu(x_row . w13[e][:, n]) * (x_row . w13[e][:, n+ID])
// BF16B: wB is bf16 [e][n][k] (precast); else fp32 [e][k][n] (fallback).
template <bool BF16B>
__global__ __launch_bounds__(256)
void gemm1_kernel(const bf16_t* __restrict__ xb, const void* __restrict__ wB,
                  const int* __restrict__ offsets, const int* __restrict__ counts,
                  const int* __restrict__ token_list, bf16_t* __restrict__ hbuf)
{
    const int e = blockIdx.y >> 6;          // / MT_MAX
    const int mt = blockIdx.y & (MT_MAX - 1);
    const int rows = counts[e];
    const int r0 = mt * BM;
    if (r0 >= rows) return;
    const int row_base = offsets[e];
    const int n0 = blockIdx.x * BN;

    __shared__ int tok_s[BM];
    __shared__ alignas(16) bf16_t As[BM][PK];
    __shared__ alignas(16) bf16_t Bg[BN][PK];
    __shared__ alignas(16) bf16_t Bu[BN][PK];

    const int tid = threadIdx.x;
    if (tid < BM) {
        int gr = row_base + r0 + tid;
        if (gr > NROWS - 1) gr = NROWS - 1;   // clamp: padded rows guarded at write
        tok_s[tid] = token_list[gr];
    }
    __syncthreads();

    const int lane = tid & 63, wv = tid >> 6;
    const int wr = wv >> 1, wc = wv & 1;
    const int ln15 = lane & 15, q = lane >> 4;

    f32x4 accG[4][2], accU[4][2];
#pragma unroll
    for (int i = 0; i < 4; ++i)
#pragma unroll
        for (int j = 0; j < 2; ++j)
#pragma unroll
            for (int c = 0; c < 4; ++c) { accG[i][j][c] = 0.f; accU[i][j][c] = 0.f; }

    // A staging: 2 threads per row, each covers 16 bf16 elements = 32 B (2x uint4)
    const int ar = tid >> 1, ac = (tid & 1) * 16;
    // B staging (bf16 path): thread -> n row tid>>2, k-offset (tid&3)*8, one uint4 each
    const int bn2 = tid >> 2, bko = (tid & 3) * 8;
    // B staging (fp32 path): float4 along n
    const int bk = tid >> 4, bn = (tid & 15) * 4;

    const float* w13f = (const float*)wB + (size_t)e * HD * (2 * ID);
    const bf16_t* w13g = (const bf16_t*)wB + (size_t)e * HD * (2 * ID)
                       + (size_t)(n0 + bn2) * HD + bko;       // gate row
    const bf16_t* w13u = w13g + (size_t)ID * HD;              // up rows offset by ID*HD

    for (int k0 = 0; k0 < HD; k0 += BK) {
        const uint4* asrc = (const uint4*)(xb + (size_t)tok_s[ar] * HD + k0 + ac);
        *(uint4*)&As[ar][ac]     = asrc[0];
        *(uint4*)&As[ar][ac + 8] = asrc[1];
        if constexpr (BF16B) {
            *(uint4*)&Bg[bn2][bko] = *(const uint4*)(w13g + k0);
            *(uint4*)&Bu[bn2][bko] = *(const uint4*)(w13u + k0);
        } else {
#pragma unroll
            for (int s = 0; s < 2; ++s) {
                const int kk = bk + 16 * s;
                const float* src = w13f + (size_t)(k0 + kk) * (2 * ID) + n0 + bn;
                const float4 g4 = *(const float4*)src;
                const float4 u4 = *(const float4*)(src + ID);
                Bg[bn + 0][kk] = (bf16_t)g4.x; Bg[bn + 1][kk] = (bf16_t)g4.y;
                Bg[bn + 2][kk] = (bf16_t)g4.z; Bg[bn + 3][kk] = (bf16_t)g4.w;
                Bu[bn + 0][kk] = (bf16_t)u4.x; Bu[bn + 1][kk] = (bf16_t)u4.y;
                Bu[bn + 2][kk] = (bf16_t)u4.z; Bu[bn + 3][kk] = (bf16_t)u4.w;
            }
        }
        __syncthreads();

        bf16x8 af[4];
#pragma unroll
        for (int i = 0; i < 4; ++i)
            af[i] = *(const bf16x8*)&As[wr * 64 + i * 16 + ln15][q * 8];
        bf16x8 bg[2], bu[2];
#pragma unroll
        for (int j = 0; j < 2; ++j) {
            bg[j] = *(const bf16x8*)&Bg[wc * 32 + j * 16 + ln15][q * 8];
            bu[j] = *(const bf16x8*)&Bu[wc * 32 + j * 16 + ln15][q * 8];
        }
#pragma unroll
        for (int i = 0; i < 4; ++i)
#pragma unroll
            for (int j = 0; j < 2; ++j) {
                accG[i][j] = __builtin_amdgcn_mfma_f32_16x16x32_bf16(af[i], bg[j], accG[i][j], 0, 0, 0);
                accU[i][j] = __builtin_amdgcn_mfma_f32_16x16x32_bf16(af[i], bu[j], accU[i][j], 0, 0, 0);
            }
        __syncthreads();
    }

    // epilogue: SwiGLU in fp32, store bf16 h. C/D: col=lane&15, row=q*4+reg
#pragma unroll
    for (int i = 0; i < 4; ++i) {
#pragma unroll
        for (int reg = 0; reg < 4; ++reg) {
            const int rr = wr * 64 + i * 16 + q * 4 + reg;
            if (r0 + rr < rows) {
                bf16_t* dst = hbuf + (size_t)(row_base + r0 + rr) * ID + n0 + wc * 32 + ln15;
#pragma unroll
                for (int j = 0; j < 2; ++j) {
                    const float g = accG[i][j][reg], u = accU[i][j][reg];
                    dst[j * 16] = (bf16_t)((g / (1.f + __expf(-g))) * u);
                }
            }
        }
    }
}

// --------------------------------------------------------- grouped GEMM2 ----
// out[token, n] += weight_row * (h_row . w2[e][:, n])
template <bool BF16B>
__global__ __launch_bounds__(256)
void gemm2_kernel(const bf16_t* __restrict__ hbuf, const void* __restrict__ wB,
                  const int* __restrict__ offsets, const int* __restrict__ counts,
                  const int* __restrict__ token_list, const float* __restrict__ row_w,
                  float* __restrict__ out)
{
    const int e = blockIdx.y >> 6;
    const int mt = blockIdx.y & (MT_MAX - 1);
    const int rows = counts[e];
    const int r0 = mt * BM;
    if (r0 >= rows) return;
    const int row_base = offsets[e];
    const int n0 = blockIdx.x * BN;

    __shared__ int tok_s[BM];
    __shared__ float rww_s[BM];
    __shared__ alignas(16) bf16_t As[BM][PK];
    __shared__ alignas(16) bf16_t Bs[BN][PK];

    const int tid = threadIdx.x;
    if (tid < BM) {
        int gr = row_base + r0 + tid;
        if (gr > NROWS - 1) gr = NROWS - 1;
        tok_s[tid] = token_list[gr];
        rww_s[tid] = row_w[gr];
    }
    __syncthreads();

    const int lane = tid & 63, wv = tid >> 6;
    const int wr = wv >> 1, wc = wv & 1;
    const int ln15 = lane & 15, q = lane >> 4;

    f32x4 acc[4][2];
#pragma unroll
    for (int i = 0; i < 4; ++i)
#pragma unroll
        for (int j = 0; j < 2; ++j)
#pragma unroll
            for (int c = 0; c < 4; ++c) acc[i][j][c] = 0.f;

    const int ar = tid >> 1, ac = (tid & 1) * 16;
    const int bn2 = tid >> 2, bko = (tid & 3) * 8;
    const int bk = tid >> 4, bn = (tid & 15) * 4;
    int grow = row_base + r0 + ar;
    if (grow > NROWS - 1) grow = NROWS - 1;
    const bf16_t* arow = hbuf + (size_t)grow * ID;

    const float* w2f = (const float*)wB + (size_t)e * ID * HD;
    const bf16_t* w2b = (const bf16_t*)wB + (size_t)e * ID * HD
                      + (size_t)(n0 + bn2) * ID + bko;

    for (int k0 = 0; k0 < ID; k0 += BK) {
        const uint4* asrc = (const uint4*)(arow + k0 + ac);
        *(uint4*)&As[ar][ac]     = asrc[0];
        *(uint4*)&As[ar][ac + 8] = asrc[1];
        if constexpr (BF16B) {
            *(uint4*)&Bs[bn2][bko] = *(const uint4*)(w2b + k0);
        } else {
#pragma unroll
            for (int s = 0; s < 2; ++s) {
                const int kk = bk + 16 * s;
                const float4 b4 = *(const float4*)(w2f + (size_t)(k0 + kk) * HD + n0 + bn);
                Bs[bn + 0][kk] = (bf16_t)b4.x; Bs[bn + 1][kk] = (bf16_t)b4.y;
                Bs[bn + 2][kk] = (bf16_t)b4.z; Bs[bn + 3][kk] = (bf16_t)b4.w;
            }
        }
        __syncthreads();

        bf16x8 af[4];
#pragma unroll
        for (int i = 0; i < 4; ++i)
            af[i] = *(const bf16x8*)&As[wr * 64 + i * 16 + ln15][q * 8];
        bf16x8 bf2[2];
#pragma unroll
        for (int j = 0; j < 2; ++j)
            bf2[j] = *(const bf16x8*)&Bs[wc * 32 + j * 16 + ln15][q * 8];
#pragma unroll
        for (int i = 0; i < 4; ++i)
#pragma unroll
            for (int j = 0; j < 2; ++j)
                acc[i][j] = __builtin_amdgcn_mfma_f32_16x16x32_bf16(af[i], bf2[j], acc[i][j], 0, 0, 0);
        __syncthreads();
    }

    // epilogue: scale by routing weight, atomicAdd into out (2 writers/elem)
#pragma unroll
    for (int i = 0; i < 4; ++i) {
#pragma unroll
        for (int reg = 0; reg < 4; ++reg) {
            const int rr = wr * 64 + i * 16 + q * 4 + reg;
            if (r0 + rr < rows) {
                const float w = rww_s[rr];
                float* dst = out + (size_t)tok_s[rr] * HD + n0 + wc * 32 + ln15;
#pragma unroll
                for (int j = 0; j < 2; ++j)
                    atomicAdd(&dst[j * 16], acc[i][j][reg] * w);
            }
        }
    }
}

// ---------------------------------------------------------------- launch ----
extern "C" void kernel_launch(void* const* d_in, const int* in_sizes, int n_in,
                              void* d_out, int out_size, void* d_ws, size_t ws_size,
                              hipStream_t stream) {
    const float* x   = (const float*)d_in[0];   // (4,2048,1024)
    const float* rw  = (const float*)d_in[1];   // (8,1024)
    const float* w13 = (const float*)d_in[2];   // (8,1024,4096)
    const float* w2  = (const float*)d_in[3];   // (8,2048,1024)
    float* out = (float*)d_out;                 // (4,2048,1024) fp32

    char* ws = (char*)d_ws;
    // ws layout
    int*   counts     = (int*)(ws + 0);
    int*   cursor     = (int*)(ws + 64);
    int*   offsets    = (int*)(ws + 128);
    int*   topk_idx   = (int*)(ws + 256);
    float* topk_w     = (float*)(ws + 256 + 1 * 65536);
    int*   token_list = (int*)(ws + 256 + 2 * 65536);
    float* row_w      = (float*)(ws + 256 + 3 * 65536);
    const size_t MB = 1024 * 1024;
    bf16_t* xb   = (bf16_t*)(ws + 1 * MB);      // 16 MB
    bf16_t* hbuf = (bf16_t*)(ws + 17 * MB);     // 64 MB
    bf16_t* w13b = (bf16_t*)(ws + 81 * MB);     // 64 MB
    bf16_t* w2b  = (bf16_t*)(ws + 145 * MB);    // 32 MB (ends at 177 MB)
    const bool use_bf16 = ws_size >= 177 * MB;

    hipMemsetAsync(ws, 0, 256, stream);                              // counts/cursor
    hipMemsetAsync(d_out, 0, (size_t)out_size * sizeof(float), stream);

    if (use_bf16) {
        dim3 gp1(2 * ID / 64, HD / 64, NEXP);   // w13: K=HD, N=2*ID
        precast_kernel<<<gp1, 256, 0, stream>>>(w13, w13b, HD, 2 * ID);
        dim3 gp2(HD / 64, ID / 64, NEXP);       // w2: K=ID, N=HD
        precast_kernel<<<gp2, 256, 0, stream>>>(w2, w2b, ID, HD);
    }

    router_kernel<<<NTOK, 256, 0, stream>>>(x, rw, xb, topk_idx, topk_w, counts);
    scan_kernel<<<1, 64, 0, stream>>>(counts, offsets, cursor);
    scatter_kernel<<<NTOK / 256, 256, 0, stream>>>(topk_idx, topk_w, cursor, token_list, row_w);

    dim3 g1(ID / BN, NEXP * MT_MAX);    // 32 x 512
    dim3 g2(HD / BN, NEXP * MT_MAX);    // 16 x 512
    if (use_bf16) {
        gemm1_kernel<true><<<g1, 256, 0, stream>>>(xb, w13b, offsets, counts, token_list, hbuf);
        gemm2_kernel<true><<<g2, 256, 0, stream>>>(hbuf, w2b, offsets, counts, token_list, row_w, out);
    } else {
        gemm1_kernel<false><<<g1, 256, 0, stream>>>(xb, w13, offsets, counts, token_list, hbuf);
        gemm2_kernel<false><<<g2, 256, 0, stream>>>(hbuf, w2, offsets, counts, token_list, row_w, out);
    }
}